// Round 6
// baseline (140.844 us; speedup 1.0000x reference)
//
#include <hip/hip_runtime.h>
#include <hip/hip_bf16.h>

typedef unsigned short u16;
typedef __attribute__((ext_vector_type(8))) short bf16x8;
typedef __attribute__((ext_vector_type(4))) float f32x4;
typedef __attribute__((ext_vector_type(8))) unsigned short u16x8;

#define GLDS(gp, lp) __builtin_amdgcn_global_load_lds( \
    (const __attribute__((address_space(1))) void*)(gp), \
    (__attribute__((address_space(3))) void*)(lp), 16, 0, 0)

__device__ __forceinline__ u16 f2b(float f) {
  unsigned u = __builtin_bit_cast(unsigned, f);
  return (u16)((u + 0x7fffu + ((u >> 16) & 1u)) >> 16);  // RNE, finite inputs
}
__device__ __forceinline__ float b2f(u16 s) {
  return __builtin_bit_cast(float, (unsigned)s << 16);
}

#define BARX() do { __builtin_amdgcn_sched_barrier(0); \
  asm volatile("s_barrier" ::: "memory"); \
  __builtin_amdgcn_sched_barrier(0); } while (0)

// ---------- kernel 0: weight f32 -> bf16 (Wp|Wc|Ws packed, Wo) ----------
__global__ __launch_bounds__(256) void convert_w(
    const float* __restrict__ Wp, const float* __restrict__ Wc,
    const float* __restrict__ Ws, const float* __restrict__ Wo,
    u16* __restrict__ wall, u16* __restrict__ wob)
{
  const long CW = 98304;    // 786432/8 packed-weight chunks
  const long i = (long)blockIdx.x * blockDim.x + threadIdx.x;  // grid covers exactly
  const float* src; u16* dst;
  if (i < CW) {
    long e = i * 8;
    int n = (int)(e >> 9), k = (int)(e & 511);
    const float* wr = (n < 512)  ? (Wp + (long)n * 512)
                    : (n < 1024) ? (Wc + (long)(n - 512) * 512)
                                 : (Ws + (long)(n - 1024) * 512);
    src = wr + k; dst = wall + e;
  } else {
    long e = (i - CW) * 8; src = Wo + e; dst = wob + e;
  }
  f32x4 v0 = *(const f32x4*)src;
  f32x4 v1 = *(const f32x4*)(src + 4);
  u16x8 o;
  o[0]=f2b(v0[0]); o[1]=f2b(v0[1]); o[2]=f2b(v0[2]); o[3]=f2b(v0[3]);
  o[4]=f2b(v1[0]); o[5]=f2b(v1[1]); o[6]=f2b(v1[2]); o[7]=f2b(v1[3]);
  *(u16x8*)dst = o;
}

// ---------- 256x256 8-phase GEMM (r5-verified core): C = A·Bw^T + bias ----------
// AF32: A is f32, converted in-flight during reg-staged A (fused convert).
// Else: A is bf16 via global_load_lds (r5 path, verbatim).
template<int NC, bool BF16OUT, bool AF32>
__global__ __launch_bounds__(512, 2) void gemm8(
    const void* __restrict__ Ain, const u16* __restrict__ Bw,
    const float* __restrict__ bias0, const float* __restrict__ bias1,
    const float* __restrict__ bias2, void* __restrict__ Cout)
{
  __shared__ alignas(16) char smem[131072];
  char* sAc = smem;            // [2][32768] A tiles: [256 rows][128 B]
  char* sBc = smem + 65536;    // [2][32768] B tiles

  const int tid = threadIdx.x;
  const int w = tid >> 6, lane = tid & 63;
  const int wr = w >> 2, wc = w & 3;          // 2 x 4 wave grid
  const int ln15 = lane & 15, g4 = lane >> 4, l7 = lane & 7;

  // --- block swizzle: XCD-chunked (nwg % 8 == 0 for both instantiations) ---
  const int nbx = NC / 256;
  const int nwg = nbx * 128;
  const int qq = nwg / 8;
  const int flat = blockIdx.x;
  const int swz = (flat & 7) * qq + (flat >> 3);
  const int bx = swz % nbx, by = swz / nbx;
  const long row0 = (long)by * 256;
  const int col0 = bx * 256;

  // --- staging geometry ---
  // LDS layout (both A and B): row r (0..255) at byte r*128; granule slot s (16B)
  // holds global K-granule s ^ (r&7)  (XOR swizzle).
  // GLDS path: thread t writes LDS byte j*8192 + t*16 -> row j*64 + t/8, slot t&7;
  //   source pre-swizzled: granule (t&7) ^ ((t>>3)&7).
  // reg-stage path (AF32): thread reads LINEAR granule t&7 of row j*64 + t/8,
  //   ds_writes to swizzled slot  -> same final content.
  const int gsw = (tid & 7) ^ ((tid >> 3) & 7);
  const float* pX = (const float*)Ain + (row0 + (tid >> 3)) * 512 + (tid & 7) * 8;
  const u16* pA = (const u16*)Ain + (row0 + (tid >> 3)) * 512 + gsw * 8;
  const u16* pB = Bw + ((long)col0 + (tid >> 3)) * 512 + gsw * 8;
  const int aw_dst = (tid >> 3) * 128 + gsw * 16;

#define STAGE_A(pp, tt) do { \
    const u16* a0_ = pA + (tt) * 64; \
    char* da_ = sAc + (pp) * 32768 + w * 1024; \
    GLDS(a0_, da_);          GLDS(a0_ + 32768, da_ + 8192); \
    GLDS(a0_ + 65536, da_ + 16384); GLDS(a0_ + 98304, da_ + 24576); \
  } while (0)
#define STAGE_B(pp, tt) do { \
    const u16* b0_ = pB + (tt) * 64; \
    char* db_ = sBc + (pp) * 32768 + w * 1024; \
    GLDS(b0_, db_);          GLDS(b0_ + 32768, db_ + 8192); \
    GLDS(b0_ + 65536, db_ + 16384); GLDS(b0_ + 98304, db_ + 24576); \
  } while (0)
#define A_ISSUE(tt) do { \
    const float* ax_ = pX + (tt) * 64; \
    _Pragma("unroll") for (int j = 0; j < 4; ++j) { \
      av[j][0] = *(const f32x4*)(ax_ + j * 32768); \
      av[j][1] = *(const f32x4*)(ax_ + j * 32768 + 4); \
    } } while (0)
#define A_WRITE(pp) do { \
    _Pragma("unroll") for (int j = 0; j < 4; ++j) { \
      u16x8 o_; \
      _Pragma("unroll") for (int e = 0; e < 4; ++e) { \
        o_[e]     = __builtin_bit_cast(u16, __float2bfloat16(av[j][0][e])); \
        o_[e + 4] = __builtin_bit_cast(u16, __float2bfloat16(av[j][1][e])); \
      } \
      *(u16x8*)(sAc + (pp) * 32768 + j * 8192 + aw_dst) = o_; \
    } } while (0)

  // --- fragment-read addressing (swizzled): row&7 == lane&7 for all frags ---
  const int gkb0 = ((0 + g4) ^ l7) * 16;   // kk=0 granule byte
  const int gkb1 = ((4 + g4) ^ l7) * 16;   // kk=1 granule byte
  const int arow = (wr * 128 + ln15) * 128;
  const int brow = (wc * 64 + ln15) * 128;

#define LOAD_A(MH) do { \
    _Pragma("unroll") for (int mf = 0; mf < 4; ++mf) { \
      aF[mf][0] = *(const bf16x8*)(bufA + (MH) * 8192 + mf * 2048 + gkb0); \
      aF[mf][1] = *(const bf16x8*)(bufA + (MH) * 8192 + mf * 2048 + gkb1); \
    } } while (0)
#define LOAD_B(NH, BF) do { \
    _Pragma("unroll") for (int nf = 0; nf < 2; ++nf) { \
      BF[nf][0] = *(const bf16x8*)(bufB + (NH) * 4096 + nf * 2048 + gkb0); \
      BF[nf][1] = *(const bf16x8*)(bufB + (NH) * 4096 + nf * 2048 + gkb1); \
    } } while (0)
#define MFMA_Q(MH, NH, BF) do { \
    _Pragma("unroll") for (int mf = 0; mf < 4; ++mf) \
    _Pragma("unroll") for (int nf = 0; nf < 2; ++nf) { \
      f32x4 c_ = acc[(MH) * 4 + mf][(NH) * 2 + nf]; \
      c_ = __builtin_amdgcn_mfma_f32_16x16x32_bf16(aF[mf][0], BF[nf][0], c_, 0, 0, 0); \
      c_ = __builtin_amdgcn_mfma_f32_16x16x32_bf16(aF[mf][1], BF[nf][1], c_, 0, 0, 0); \
      acc[(MH) * 4 + mf][(NH) * 2 + nf] = c_; \
    } } while (0)

  f32x4 acc[8][4] = {};
  f32x4 av[4][2];

  // prologue: stage K-tile 0 into buf 0
  if constexpr (AF32) { A_ISSUE(0); } else { STAGE_A(0, 0); }
  STAGE_B(0, 0);
  if constexpr (AF32) {
    A_WRITE(0);  // compiler inserts the vmcnt waits for av
    asm volatile("s_waitcnt vmcnt(0)" ::: "memory");
    asm volatile("s_waitcnt lgkmcnt(0)" ::: "memory");
  } else {
    asm volatile("s_waitcnt vmcnt(0)" ::: "memory");
  }
  BARX();

  for (int t = 0; t < 8; ++t) {          // K = 512 / BK = 64
    const int p = t & 1;
    const char* bufA = sAc + p * 32768 + arow;
    const char* bufB = sBc + p * 32768 + brow;
    bf16x8 aF[4][2], bFa[2][2], bFb[2][2];

    // phase 0: quadrant (m0, n0); issue next tile's stage loads
    LOAD_A(0); LOAD_B(0, bFa);
    if (t < 7) {
      if constexpr (AF32) { A_ISSUE(t + 1); } else { STAGE_A(p ^ 1, t + 1); }
      STAGE_B(p ^ 1, t + 1);
    }
    BARX();
    __builtin_amdgcn_s_setprio(1); MFMA_Q(0, 0, bFa); __builtin_amdgcn_s_setprio(0);
    BARX();
    // phase 1: quadrant (m0, n1)
    LOAD_B(1, bFb);
    BARX();
    __builtin_amdgcn_s_setprio(1); MFMA_Q(0, 1, bFb); __builtin_amdgcn_s_setprio(0);
    BARX();
    // phase 2: quadrant (m1, n1)
    LOAD_A(1);
    BARX();
    __builtin_amdgcn_s_setprio(1); MFMA_Q(1, 1, bFb); __builtin_amdgcn_s_setprio(0);
    BARX();
    // phase 3: quadrant (m1, n0) — no new loads
    __builtin_amdgcn_s_setprio(1); MFMA_Q(1, 0, bFa); __builtin_amdgcn_s_setprio(0);
    if (t < 7) {
      if constexpr (AF32) {
        A_WRITE(p ^ 1);  // waits for av (loads aged 3 phases), then ds_write
        asm volatile("s_waitcnt vmcnt(0)" ::: "memory");   // B GLDS drained
        asm volatile("s_waitcnt lgkmcnt(0)" ::: "memory"); // A writes visible
      } else {
        asm volatile("s_waitcnt vmcnt(0)" ::: "memory");
      }
      BARX();
    }
  }

  // ---- epilogue (r5-verified): per-wave LDS staging -> contiguous stores ----
  // acc[mi][n][j]: local row = mi*16 + g4*4 + j (0..127), local col = n*16 + ln15.
  __syncthreads();   // full drain; everyone done with sA/sB
  const long rgb = row0 + wr * 128;
  const int cgb = col0 + wc * 64;
  if (BF16OUT) {
    u16* sc = (u16*)(smem + (w << 14));      // 16 KiB/wave: [128][64] u16
#pragma unroll
    for (int n = 0; n < 4; ++n) {
      const int colg = cgb + ln15 + n * 16;
      const float* bp_ = (NC == 512) ? bias0
                         : (colg < 512 ? bias0 : (colg < 1024 ? bias1 : bias2));
      const float bv = bp_[colg & 511];
      const int c = ln15 + n * 16;
      const int gsl = c >> 3, co = c & 7;
#pragma unroll
      for (int mi = 0; mi < 8; ++mi)
#pragma unroll
        for (int j = 0; j < 4; ++j) {
          const int r = mi * 16 + (g4 << 2) + j;
          sc[r * 64 + (((gsl ^ (r & 7)) << 3) | co)] = f2b(acc[mi][n][j] + bv);
        }
    }
    asm volatile("s_waitcnt lgkmcnt(0)" ::: "memory");
    __builtin_amdgcn_sched_barrier(0);
#pragma unroll
    for (int it = 0; it < 16; ++it) {
      const int rr = it * 8 + (lane >> 3);
      const int gl = lane & 7;
      u16x8 v = *(const u16x8*)(sc + rr * 64 + ((gl ^ (rr & 7)) << 3));
      *(u16x8*)((u16*)Cout + (rgb + rr) * NC + cgb + gl * 8) = v;
    }
  } else {
    float* scf = (float*)(smem + (w << 14));  // 16 KiB/wave: [64][64] f32, 2 passes
#pragma unroll
    for (int h = 0; h < 2; ++h) {
#pragma unroll
      for (int n = 0; n < 4; ++n) {
        const int colg = cgb + ln15 + n * 16;
        const float bv = bias0[colg & 511];
        const int c = ln15 + n * 16;
        const int gsl = c >> 2, co = c & 3;
#pragma unroll
        for (int mf = 0; mf < 4; ++mf)
#pragma unroll
          for (int j = 0; j < 4; ++j) {
            const int r = mf * 16 + (g4 << 2) + j;
            scf[r * 64 + (((gsl ^ (r & 7)) << 2) | co)] = acc[h * 4 + mf][n][j] + bv;
          }
      }
      asm volatile("s_waitcnt lgkmcnt(0)" ::: "memory");
      __builtin_amdgcn_sched_barrier(0);
#pragma unroll
      for (int it = 0; it < 16; ++it) {
        const int rr = it * 4 + (lane >> 4);
        const int gl = lane & 15;
        f32x4 v = *(const f32x4*)(scf + rr * 64 + ((gl ^ (rr & 7)) << 2));
        *(f32x4*)((float*)Cout + (rgb + h * 64 + rr) * NC + cgb + gl * 4) = v;
      }
      asm volatile("s_waitcnt lgkmcnt(0)" ::: "memory");
      __builtin_amdgcn_sched_barrier(0);
    }
  }
#undef STAGE_A
#undef STAGE_B
#undef A_ISSUE
#undef A_WRITE
#undef LOAD_A
#undef LOAD_B
#undef MFMA_Q
}

// ---------- attention: per-token 8x8 head-mix, one wave per token ----------
__global__ __launch_bounds__(256) void attn_k(const u16* __restrict__ PCS,
                                              u16* __restrict__ OUT)
{
  // per-wave f32 scratch: p[8][68], c[8][68], s[512], attn[64]  (pad 68 kills bank conflicts)
  __shared__ float L[4][1664];
  const int w = threadIdx.x >> 6, lane = threadIdx.x & 63;
  const long token = (long)blockIdx.x * 4 + w;
  float* Lw = L[w];
  const int C0 = 544, S0 = 1088, AT0 = 1600;
  const u16* rowp = PCS + token * 1536;
#pragma unroll
  for (int q = 0; q < 3; ++q) {
    u16x8 v = *(const u16x8*)(rowp + q * 512 + lane * 8);
    float* dst = (q < 2) ? (Lw + q * 544 + (lane >> 3) * 68 + (lane & 7) * 8)
                         : (Lw + S0 + lane * 8);
    f32x4 a = {b2f(v[0]), b2f(v[1]), b2f(v[2]), b2f(v[3])};
    f32x4 b = {b2f(v[4]), b2f(v[5]), b2f(v[6]), b2f(v[7])};
    *(f32x4*)dst = a;
    *(f32x4*)(dst + 4) = b;
  }
  // all data wave-local: no __syncthreads needed (wave-synchronous + in-order DS)
  const int h = lane >> 3, t = lane & 7;
  float sc = 0.f;
#pragma unroll
  for (int d = 0; d < 64; d += 4) {
    f32x4 pv = *(const f32x4*)(Lw + h * 68 + d);
    f32x4 cv = *(const f32x4*)(Lw + C0 + t * 68 + d);
    sc += pv[0]*cv[0] + pv[1]*cv[1] + pv[2]*cv[2] + pv[3]*cv[3];
  }
  sc *= 0.125f;  // 1/sqrt(D), D=64
  float mx = sc;
  mx = fmaxf(mx, __shfl_xor(mx, 1));
  mx = fmaxf(mx, __shfl_xor(mx, 2));
  mx = fmaxf(mx, __shfl_xor(mx, 4));
  float e = __expf(sc - mx);
  float sm = e;
  sm += __shfl_xor(sm, 1);
  sm += __shfl_xor(sm, 2);
  sm += __shfl_xor(sm, 4);
  Lw[AT0 + lane] = e / sm;
  float o[8] = {0, 0, 0, 0, 0, 0, 0, 0};
#pragma unroll
  for (int tt = 0; tt < 8; ++tt) {
    const float av = Lw[AT0 + h * 8 + tt];
    f32x4 s0 = *(const f32x4*)(Lw + S0 + tt * 64 + t * 8);
    f32x4 s1 = *(const f32x4*)(Lw + S0 + tt * 64 + t * 8 + 4);
    o[0] += av * s0[0]; o[1] += av * s0[1]; o[2] += av * s0[2]; o[3] += av * s0[3];
    o[4] += av * s1[0]; o[5] += av * s1[1]; o[6] += av * s1[2]; o[7] += av * s1[3];
  }
  u16x8 ov;
#pragma unroll
  for (int j = 0; j < 8; ++j) ov[j] = f2b(o[j]);
  // out element index within token = h*64 + (t*8+j) = lane*8+j -> coalesced 16B/lane
  *(u16x8*)(OUT + token * 512 + lane * 8) = ov;
}

extern "C" void kernel_launch(void* const* d_in, const int* in_sizes, int n_in,
                              void* d_out, int out_size, void* d_ws, size_t ws_size,
                              hipStream_t stream) {
  const float* x  = (const float*)d_in[0];
  const float* Wp = (const float*)d_in[1];
  const float* bp = (const float*)d_in[2];
  const float* Wc = (const float*)d_in[3];
  const float* bc = (const float*)d_in[4];
  const float* Ws = (const float*)d_in[5];
  const float* bs = (const float*)d_in[6];
  const float* Wo = (const float*)d_in[7];
  const float* bo = (const float*)d_in[8];

  char* ws = (char*)d_ws;
  u16* wall = (u16*)ws;                      //  1,572,864 B  ([1536][512] Wp|Wc|Ws)
  u16* wob  = (u16*)(ws + 1572864);          //    524,288 B  ([512][512] Wo)
  u16* pcs  = (u16*)(ws + 2097152);          // 100,663,296 B ([32768][1536] p|c|s)
  u16* outb = (u16*)(ws + 102760448);        // 33,554,432 B  (attn out, bf16)

  convert_w<<<512, 256, 0, stream>>>(Wp, Wc, Ws, Wo, wall, wob);
  gemm8<1536, true, true><<<768, 512, 0, stream>>>(x, wall, bp, bc, bs, pcs);
  attn_k<<<8192, 256, 0, stream>>>(pcs, outb);
  gemm8<512, false, false><<<256, 512, 0, stream>>>(outb, wob, bo, bo, bo, d_out);
}

// Round 7
// 136.483 us; speedup vs baseline: 1.0320x; 1.0320x over previous
//
#include <hip/hip_runtime.h>
#include <hip/hip_bf16.h>

typedef unsigned short u16;
typedef __attribute__((ext_vector_type(8))) short bf16x8;
typedef __attribute__((ext_vector_type(4))) float f32x4;
typedef __attribute__((ext_vector_type(8))) unsigned short u16x8;

#define GLDS(gp, lp) __builtin_amdgcn_global_load_lds( \
    (const __attribute__((address_space(1))) void*)(gp), \
    (__attribute__((address_space(3))) void*)(lp), 16, 0, 0)

__device__ __forceinline__ u16 f2b(float f) {
  unsigned u = __builtin_bit_cast(unsigned, f);
  return (u16)((u + 0x7fffu + ((u >> 16) & 1u)) >> 16);  // RNE, finite inputs
}
__device__ __forceinline__ float b2f(u16 s) {
  return __builtin_bit_cast(float, (unsigned)s << 16);
}

#define BARX() do { __builtin_amdgcn_sched_barrier(0); \
  asm volatile("s_barrier" ::: "memory"); \
  __builtin_amdgcn_sched_barrier(0); } while (0)

// ---------- kernel 0: f32 -> bf16 conversion (x, Wp|Wc|Ws packed, Wo) ----------
__global__ __launch_bounds__(256) void convert_k(
    const float* __restrict__ x, const float* __restrict__ Wp,
    const float* __restrict__ Wc, const float* __restrict__ Ws,
    const float* __restrict__ Wo, u16* __restrict__ xb,
    u16* __restrict__ wall, u16* __restrict__ wob)
{
  const long CX = 2097152;  // 16777216/8 x-chunks
  const long CW = 98304;    // 786432/8 packed-weight chunks
  const long CO = 32768;    // 262144/8 Wo chunks
  const long total = CX + CW + CO;
  for (long i = (long)blockIdx.x * blockDim.x + threadIdx.x; i < total;
       i += (long)gridDim.x * blockDim.x) {
    const float* src; u16* dst;
    if (i < CX) {
      src = x + i * 8; dst = xb + i * 8;
    } else if (i < CX + CW) {
      long e = (i - CX) * 8;
      int n = (int)(e >> 9), k = (int)(e & 511);
      const float* wr = (n < 512)  ? (Wp + (long)n * 512)
                      : (n < 1024) ? (Wc + (long)(n - 512) * 512)
                                   : (Ws + (long)(n - 1024) * 512);
      src = wr + k; dst = wall + e;
    } else {
      long e = (i - CX - CW) * 8; src = Wo + e; dst = wob + e;
    }
    f32x4 v0 = *(const f32x4*)src;
    f32x4 v1 = *(const f32x4*)(src + 4);
    u16x8 o;
    o[0]=f2b(v0[0]); o[1]=f2b(v0[1]); o[2]=f2b(v0[2]); o[3]=f2b(v0[3]);
    o[4]=f2b(v1[0]); o[5]=f2b(v1[1]); o[6]=f2b(v1[2]); o[7]=f2b(v1[3]);
    *(u16x8*)dst = o;
  }
}

// ---------- 256x256 GEMM (r5-verified core, barriers relaxed): C = A·Bw^T + bias ----------
// A: [M][512] bf16, Bw: [NC][512] bf16. 512 threads = 8 waves (2M x 4N),
// per-wave 128x64 out, BK=64, dbuf LDS 128 KiB, XOR-granule swizzle (both-sides).
// ONLY change vs r5 (passed, 136us): intra-tile barriers removed — within a tile all
// ds_reads hit buf p and all GLDS writes hit buf p^1, so the double-buffer invariant
// needs exactly one vmcnt(0)+barrier per tile. Waves free-run -> LDS reads of one
// wave overlap MFMAs of the other (per-SIMD), instead of alternating in lockstep.
template<int NC, bool BF16OUT>
__global__ __launch_bounds__(512, 2) void gemm8(
    const u16* __restrict__ A, const u16* __restrict__ Bw,
    const float* __restrict__ bias0, const float* __restrict__ bias1,
    const float* __restrict__ bias2, void* __restrict__ Cout)
{
  __shared__ alignas(16) char smem[131072];
  char* sAc = smem;            // [2][32768] A tiles: [256 rows][128 B]
  char* sBc = smem + 65536;    // [2][32768] B tiles

  const int tid = threadIdx.x;
  const int w = tid >> 6, lane = tid & 63;
  const int wr = w >> 2, wc = w & 3;          // 2 x 4 wave grid
  const int ln15 = lane & 15, g4 = lane >> 4, l7 = lane & 7;

  // --- block swizzle: XCD-chunked (nwg % 8 == 0 for both instantiations) ---
  const int nbx = NC / 256;
  const int nwg = nbx * 128;
  const int qq = nwg / 8;
  const int flat = blockIdx.x;
  const int swz = (flat & 7) * qq + (flat >> 3);
  const int bx = swz % nbx, by = swz / nbx;
  const long row0 = (long)by * 256;
  const int col0 = bx * 256;

  // --- staging source pointers (inverse-swizzled global, linear LDS dest) ---
  // thread writes LDS bytes L = j*8192 + tid*16 -> row r = j*64 + tid/8,
  // slot s = tid&7; slot s of row r must hold global granule s ^ (r&7).
  const int gsw = (tid & 7) ^ ((tid >> 3) & 7);
  const u16* pA = A + (row0 + (tid >> 3)) * 512 + gsw * 8;
  const u16* pB = Bw + ((long)col0 + (tid >> 3)) * 512 + gsw * 8;

#define STAGE(pp, tt) do { \
    const u16* a0_ = pA + (tt) * 64; const u16* b0_ = pB + (tt) * 64; \
    char* da_ = sAc + (pp) * 32768 + w * 1024; \
    char* db_ = sBc + (pp) * 32768 + w * 1024; \
    GLDS(a0_, da_);          GLDS(a0_ + 32768, da_ + 8192); \
    GLDS(a0_ + 65536, da_ + 16384); GLDS(a0_ + 98304, da_ + 24576); \
    GLDS(b0_, db_);          GLDS(b0_ + 32768, db_ + 8192); \
    GLDS(b0_ + 65536, db_ + 16384); GLDS(b0_ + 98304, db_ + 24576); \
  } while (0)

  // --- fragment-read addressing (swizzled): row&7 == lane&7 for all frags ---
  const int gkb0 = ((0 + g4) ^ l7) * 16;   // kk=0 granule byte
  const int gkb1 = ((4 + g4) ^ l7) * 16;   // kk=1 granule byte
  const int arow = (wr * 128 + ln15) * 128;
  const int brow = (wc * 64 + ln15) * 128;

#define LOAD_A(MH) do { \
    _Pragma("unroll") for (int mf = 0; mf < 4; ++mf) { \
      aF[mf][0] = *(const bf16x8*)(bufA + (MH) * 8192 + mf * 2048 + gkb0); \
      aF[mf][1] = *(const bf16x8*)(bufA + (MH) * 8192 + mf * 2048 + gkb1); \
    } } while (0)
#define LOAD_B(NH, BF) do { \
    _Pragma("unroll") for (int nf = 0; nf < 2; ++nf) { \
      BF[nf][0] = *(const bf16x8*)(bufB + (NH) * 4096 + nf * 2048 + gkb0); \
      BF[nf][1] = *(const bf16x8*)(bufB + (NH) * 4096 + nf * 2048 + gkb1); \
    } } while (0)
#define MFMA_Q(MH, NH, BF) do { \
    _Pragma("unroll") for (int mf = 0; mf < 4; ++mf) \
    _Pragma("unroll") for (int nf = 0; nf < 2; ++nf) { \
      f32x4 c_ = acc[(MH) * 4 + mf][(NH) * 2 + nf]; \
      c_ = __builtin_amdgcn_mfma_f32_16x16x32_bf16(aF[mf][0], BF[nf][0], c_, 0, 0, 0); \
      c_ = __builtin_amdgcn_mfma_f32_16x16x32_bf16(aF[mf][1], BF[nf][1], c_, 0, 0, 0); \
      acc[(MH) * 4 + mf][(NH) * 2 + nf] = c_; \
    } } while (0)

  f32x4 acc[8][4] = {};

  // prologue: stage K-tile 0 into buf 0
  STAGE(0, 0);
  asm volatile("s_waitcnt vmcnt(0)" ::: "memory");
  BARX();

  for (int t = 0; t < 8; ++t) {          // K = 512 / BK = 64
    const int p = t & 1;
    const char* bufA = sAc + p * 32768 + arow;
    const char* bufB = sBc + p * 32768 + brow;
    bf16x8 aF[4][2], bFa[2][2], bFb[2][2];

    // prefetch next K-tile first: 8 GLDS stay in flight across the whole tile
    if (t < 7) STAGE(p ^ 1, t + 1);
    __builtin_amdgcn_sched_barrier(0);   // pin GLDS issue above the compute body

    // tile body: no barriers — reads hit buf p only, writes hit p^1 only
    LOAD_A(0); LOAD_B(0, bFa);
    __builtin_amdgcn_s_setprio(1); MFMA_Q(0, 0, bFa); __builtin_amdgcn_s_setprio(0);
    LOAD_B(1, bFb);
    __builtin_amdgcn_s_setprio(1); MFMA_Q(0, 1, bFb); __builtin_amdgcn_s_setprio(0);
    LOAD_A(1);
    __builtin_amdgcn_s_setprio(1); MFMA_Q(1, 1, bFb); MFMA_Q(1, 0, bFa);
    __builtin_amdgcn_s_setprio(0);

    if (t < 7) {
      asm volatile("s_waitcnt vmcnt(0)" ::: "memory");  // next tile fully staged
      BARX();                                           // buffer-swap barrier
    }
  }

  // ---- epilogue (r5-verified): per-wave LDS staging -> contiguous stores ----
  // acc[mi][n][j]: local row = mi*16 + g4*4 + j (0..127), local col = n*16 + ln15.
  __syncthreads();   // full drain; everyone done with sA/sB
  const long rgb = row0 + wr * 128;
  const int cgb = col0 + wc * 64;
  if (BF16OUT) {
    u16* sc = (u16*)(smem + (w << 14));      // 16 KiB/wave: [128][64] u16
#pragma unroll
    for (int n = 0; n < 4; ++n) {
      const int colg = cgb + ln15 + n * 16;
      const float* bp_ = (NC == 512) ? bias0
                         : (colg < 512 ? bias0 : (colg < 1024 ? bias1 : bias2));
      const float bv = bp_[colg & 511];
      const int c = ln15 + n * 16;
      const int gsl = c >> 3, co = c & 7;
#pragma unroll
      for (int mi = 0; mi < 8; ++mi)
#pragma unroll
        for (int j = 0; j < 4; ++j) {
          const int r = mi * 16 + (g4 << 2) + j;
          sc[r * 64 + (((gsl ^ (r & 7)) << 3) | co)] = f2b(acc[mi][n][j] + bv);
        }
    }
    asm volatile("s_waitcnt lgkmcnt(0)" ::: "memory");
    __builtin_amdgcn_sched_barrier(0);
#pragma unroll
    for (int it = 0; it < 16; ++it) {
      const int rr = it * 8 + (lane >> 3);
      const int gl = lane & 7;
      u16x8 v = *(const u16x8*)(sc + rr * 64 + ((gl ^ (rr & 7)) << 3));
      *(u16x8*)((u16*)Cout + (rgb + rr) * NC + cgb + gl * 8) = v;
    }
  } else {
    float* scf = (float*)(smem + (w << 14));  // 16 KiB/wave: [64][64] f32, 2 passes
#pragma unroll
    for (int h = 0; h < 2; ++h) {
#pragma unroll
      for (int n = 0; n < 4; ++n) {
        const int colg = cgb + ln15 + n * 16;
        const float bv = bias0[colg & 511];
        const int c = ln15 + n * 16;
        const int gsl = c >> 2, co = c & 3;
#pragma unroll
        for (int mf = 0; mf < 4; ++mf)
#pragma unroll
          for (int j = 0; j < 4; ++j) {
            const int r = mf * 16 + (g4 << 2) + j;
            scf[r * 64 + (((gsl ^ (r & 7)) << 2) | co)] = acc[h * 4 + mf][n][j] + bv;
          }
      }
      asm volatile("s_waitcnt lgkmcnt(0)" ::: "memory");
      __builtin_amdgcn_sched_barrier(0);
#pragma unroll
      for (int it = 0; it < 16; ++it) {
        const int rr = it * 4 + (lane >> 4);
        const int gl = lane & 15;
        f32x4 v = *(const f32x4*)(scf + rr * 64 + ((gl ^ (rr & 7)) << 2));
        *(f32x4*)((float*)Cout + (rgb + h * 64 + rr) * NC + cgb + gl * 4) = v;
      }
      asm volatile("s_waitcnt lgkmcnt(0)" ::: "memory");
      __builtin_amdgcn_sched_barrier(0);
    }
  }
#undef STAGE
#undef LOAD_A
#undef LOAD_B
#undef MFMA_Q
}

// ---------- attention: per-token 8x8 head-mix, one wave per token ----------
__global__ __launch_bounds__(256) void attn_k(const u16* __restrict__ PCS,
                                              u16* __restrict__ OUT)
{
  // per-wave f32 scratch: p[8][68], c[8][68], s[512], attn[64]  (pad 68 kills bank conflicts)
  __shared__ float L[4][1664];
  const int w = threadIdx.x >> 6, lane = threadIdx.x & 63;
  const long token = (long)blockIdx.x * 4 + w;
  float* Lw = L[w];
  const int C0 = 544, S0 = 1088, AT0 = 1600;
  const u16* rowp = PCS + token * 1536;
#pragma unroll
  for (int q = 0; q < 3; ++q) {
    u16x8 v = *(const u16x8*)(rowp + q * 512 + lane * 8);
    float* dst = (q < 2) ? (Lw + q * 544 + (lane >> 3) * 68 + (lane & 7) * 8)
                         : (Lw + S0 + lane * 8);
    f32x4 a = {b2f(v[0]), b2f(v[1]), b2f(v[2]), b2f(v[3])};
    f32x4 b = {b2f(v[4]), b2f(v[5]), b2f(v[6]), b2f(v[7])};
    *(f32x4*)dst = a;
    *(f32x4*)(dst + 4) = b;
  }
  // all data wave-local: no __syncthreads needed (wave-synchronous + in-order DS)
  const int h = lane >> 3, t = lane & 7;
  float sc = 0.f;
#pragma unroll
  for (int d = 0; d < 64; d += 4) {
    f32x4 pv = *(const f32x4*)(Lw + h * 68 + d);
    f32x4 cv = *(const f32x4*)(Lw + C0 + t * 68 + d);
    sc += pv[0]*cv[0] + pv[1]*cv[1] + pv[2]*cv[2] + pv[3]*cv[3];
  }
  sc *= 0.125f;  // 1/sqrt(D), D=64
  float mx = sc;
  mx = fmaxf(mx, __shfl_xor(mx, 1));
  mx = fmaxf(mx, __shfl_xor(mx, 2));
  mx = fmaxf(mx, __shfl_xor(mx, 4));
  float e = __expf(sc - mx);
  float sm = e;
  sm += __shfl_xor(sm, 1);
  sm += __shfl_xor(sm, 2);
  sm += __shfl_xor(sm, 4);
  Lw[AT0 + lane] = e / sm;
  float o[8] = {0, 0, 0, 0, 0, 0, 0, 0};
#pragma unroll
  for (int tt = 0; tt < 8; ++tt) {
    const float av = Lw[AT0 + h * 8 + tt];
    f32x4 s0 = *(const f32x4*)(Lw + S0 + tt * 64 + t * 8);
    f32x4 s1 = *(const f32x4*)(Lw + S0 + tt * 64 + t * 8 + 4);
    o[0] += av * s0[0]; o[1] += av * s0[1]; o[2] += av * s0[2]; o[3] += av * s0[3];
    o[4] += av * s1[0]; o[5] += av * s1[1]; o[6] += av * s1[2]; o[7] += av * s1[3];
  }
  u16x8 ov;
#pragma unroll
  for (int j = 0; j < 8; ++j) ov[j] = f2b(o[j]);
  // out element index within token = h*64 + (t*8+j) = lane*8+j -> coalesced 16B/lane
  *(u16x8*)(OUT + token * 512 + lane * 8) = ov;
}

extern "C" void kernel_launch(void* const* d_in, const int* in_sizes, int n_in,
                              void* d_out, int out_size, void* d_ws, size_t ws_size,
                              hipStream_t stream) {
  const float* x  = (const float*)d_in[0];
  const float* Wp = (const float*)d_in[1];
  const float* bp = (const float*)d_in[2];
  const float* Wc = (const float*)d_in[3];
  const float* bc = (const float*)d_in[4];
  const float* Ws = (const float*)d_in[5];
  const float* bs = (const float*)d_in[6];
  const float* Wo = (const float*)d_in[7];
  const float* bo = (const float*)d_in[8];

  char* ws = (char*)d_ws;
  u16* xb   = (u16*)ws;                      // 33,554,432 B  (x as bf16)
  u16* wall = (u16*)(ws + 33554432);         //  1,572,864 B  ([1536][512] Wp|Wc|Ws)
  u16* wob  = (u16*)(ws + 35127296);         //    524,288 B  ([512][512] Wo)
  u16* pcs  = (u16*)(ws + 35651584);         // 100,663,296 B ([32768][1536] p|c|s)
  u16* outb = xb;                            // overlay: xb dead after gemm1

  convert_k<<<2048, 256, 0, stream>>>(x, Wp, Wc, Ws, Wo, xb, wall, wob);
  gemm8<1536, true><<<768, 512, 0, stream>>>(xb, wall, bp, bc, bs, pcs);
  attn_k<<<8192, 256, 0, stream>>>(pcs, outb);
  gemm8<512, false><<<256, 512, 0, stream>>>(outb, wob, bo, bo, bo, d_out);
}

// Round 8
// 136.457 us; speedup vs baseline: 1.0322x; 1.0002x over previous
//
#include <hip/hip_runtime.h>
#include <hip/hip_bf16.h>

typedef unsigned short u16;
typedef __attribute__((ext_vector_type(8))) short bf16x8;
typedef __attribute__((ext_vector_type(4))) float f32x4;
typedef __attribute__((ext_vector_type(8))) unsigned short u16x8;

#define GLDS(gp, lp) __builtin_amdgcn_global_load_lds( \
    (const __attribute__((address_space(1))) void*)(gp), \
    (__attribute__((address_space(3))) void*)(lp), 16, 0, 0)

__device__ __forceinline__ u16 f2b(float f) {
  unsigned u = __builtin_bit_cast(unsigned, f);
  return (u16)((u + 0x7fffu + ((u >> 16) & 1u)) >> 16);  // RNE, finite inputs
}
__device__ __forceinline__ float b2f(u16 s) {
  return __builtin_bit_cast(float, (unsigned)s << 16);
}

#define BARX() do { __builtin_amdgcn_sched_barrier(0); \
  asm volatile("s_barrier" ::: "memory"); \
  __builtin_amdgcn_sched_barrier(0); } while (0)

// ---------- kernel 0: f32 -> bf16 conversion (x, Wp|Wc|Ws packed, Wo) ----------
__global__ __launch_bounds__(256) void convert_k(
    const float* __restrict__ x, const float* __restrict__ Wp,
    const float* __restrict__ Wc, const float* __restrict__ Ws,
    const float* __restrict__ Wo, u16* __restrict__ xb,
    u16* __restrict__ wall, u16* __restrict__ wob)
{
  const long CX = 2097152;  // 16777216/8 x-chunks
  const long CW = 98304;    // 786432/8 packed-weight chunks
  const long CO = 32768;    // 262144/8 Wo chunks
  const long total = CX + CW + CO;
  for (long i = (long)blockIdx.x * blockDim.x + threadIdx.x; i < total;
       i += (long)gridDim.x * blockDim.x) {
    const float* src; u16* dst;
    if (i < CX) {
      src = x + i * 8; dst = xb + i * 8;
    } else if (i < CX + CW) {
      long e = (i - CX) * 8;
      int n = (int)(e >> 9), k = (int)(e & 511);
      const float* wr = (n < 512)  ? (Wp + (long)n * 512)
                      : (n < 1024) ? (Wc + (long)(n - 512) * 512)
                                   : (Ws + (long)(n - 1024) * 512);
      src = wr + k; dst = wall + e;
    } else {
      long e = (i - CX - CW) * 8; src = Wo + e; dst = wob + e;
    }
    f32x4 v0 = *(const f32x4*)src;
    f32x4 v1 = *(const f32x4*)(src + 4);
    u16x8 o;
    o[0]=f2b(v0[0]); o[1]=f2b(v0[1]); o[2]=f2b(v0[2]); o[3]=f2b(v0[3]);
    o[4]=f2b(v1[0]); o[5]=f2b(v1[1]); o[6]=f2b(v1[2]); o[7]=f2b(v1[3]);
    *(u16x8*)dst = o;
  }
}

// ---------- 256x256 GEMM, counted-vmcnt 8-phase schedule: C = A·Bw^T + bias ----------
// A: [M][512] bf16, Bw: [NC][512] bf16. 512 threads = 8 waves (2M x 4N),
// per-wave 128x64 out, BK=64, LDS 128 KiB = 2 bufs x (A:2 half x 128 x 128B +
// B: same). Halves are CONSUMPTION-ALIGNED: A-half MH holds rows MH*128+wr*64+s
// (read only by quadrant MH); B-half NH holds rows NH*128+wc*32+s.
// Per phase: {ds_read frags, stage one half (2 GLDS) into region dead >=1 phase,
// setprio MFMA quadrant, vmcnt(10), barrier}. Stage->read gap >= 6 phases for
// every half; vmcnt(10) (= 5 halves in flight) + barrier => landed, all waves.
// Never vmcnt(0) in the steady loop (T4). Last iteration: stages suppressed,
// vmcnt(2) phases 1-5, vmcnt(0) phases 6-8.
template<int NC, bool BF16OUT>
__global__ __launch_bounds__(512, 2) void gemm8(
    const u16* __restrict__ A, const u16* __restrict__ Bw,
    const float* __restrict__ bias0, const float* __restrict__ bias1,
    const float* __restrict__ bias2, void* __restrict__ Cout)
{
  __shared__ alignas(16) char smem[131072];
  char* sAc = smem;            // [2 buf][2 half][128 rows][128 B]
  char* sBc = smem + 65536;

  const int tid = threadIdx.x;
  const int w = tid >> 6, lane = tid & 63;
  const int wr = w >> 2, wc = w & 3;          // 2 x 4 wave grid
  const int ln15 = lane & 15, g4 = lane >> 4, l7 = lane & 7;

  // --- block swizzle: XCD-chunked (nwg % 8 == 0 for both instantiations) ---
  const int nbx = NC / 256;
  const int nwg = nbx * 128;
  const int qq = nwg / 8;
  const int flat = blockIdx.x;
  const int swz = (flat & 7) * qq + (flat >> 3);
  const int bx = swz % nbx, by = swz / nbx;
  const long row0 = (long)by * 256;
  const int col0 = bx * 256;

  // --- staging source pointers ---
  // Thread t8 = tid>>3 (0..63), slot = tid&7. Each stage call site j covers LDS
  // local rows j*64 + t8 of a half; slot s of local row lr holds global K-granule
  // s ^ (lr&7)  ((j*64+t8)&7 == t8&7).
  // A half h: local row lr -> global row row0 + (lr>>6)*128 + h*64 + (lr&63).
  // B half h: local row lr -> global row col0 + (lr>>5)*64 + h*32 + (lr&31).
  const int t8 = tid >> 3;
  const int gsw = (tid & 7) ^ (t8 & 7);
  const u16* pA = A + (row0 + t8) * 512 + gsw * 8;            // + j*65536 + h*32768 + t*64
  const u16* pB = Bw + ((long)col0 + (t8 >> 5) * 64 + (t8 & 31)) * 512 + gsw * 8;  // + j*65536 + h*16384 + t*64

#define STG_A(bb, h, t) do { \
    const u16* s_ = pA + (h) * 32768 + (t) * 64; \
    char* d_ = sAc + (bb) * 32768 + (h) * 16384 + w * 1024; \
    GLDS(s_, d_); GLDS(s_ + 65536, d_ + 8192); \
  } while (0)
#define STG_B(bb, h, t) do { \
    const u16* s_ = pB + (h) * 16384 + (t) * 64; \
    char* d_ = sBc + (bb) * 32768 + (h) * 16384 + w * 1024; \
    GLDS(s_, d_); GLDS(s_ + 65536, d_ + 8192); \
  } while (0)

  // --- fragment reads (swizzled): local row&7 == ln15&7 for all frags ---
  const int gkb0 = (g4 ^ l7) << 4;          // kk=0 swizzled granule byte
  const int gkb1 = ((g4 + 4) ^ l7) << 4;    // kk=1
  const int aoff = (wr * 64 + ln15) * 128;  // within A half
  const int boff = (wc * 32 + ln15) * 128;  // within B half

#define LOAD_A(bb, MH) do { \
    const char* ba_ = sAc + (bb) * 32768 + (MH) * 16384 + aoff; \
    _Pragma("unroll") for (int mf = 0; mf < 4; ++mf) { \
      aF[mf][0] = *(const bf16x8*)(ba_ + mf * 2048 + gkb0); \
      aF[mf][1] = *(const bf16x8*)(ba_ + mf * 2048 + gkb1); \
    } } while (0)
#define LOAD_B(bb, NH, BF) do { \
    const char* bb_ = sBc + (bb) * 32768 + (NH) * 16384 + boff; \
    _Pragma("unroll") for (int nf = 0; nf < 2; ++nf) { \
      BF[nf][0] = *(const bf16x8*)(bb_ + nf * 2048 + gkb0); \
      BF[nf][1] = *(const bf16x8*)(bb_ + nf * 2048 + gkb1); \
    } } while (0)
#define MFMA_Q(MH, NH, BF) do { \
    __builtin_amdgcn_s_setprio(1); \
    _Pragma("unroll") for (int mf = 0; mf < 4; ++mf) \
    _Pragma("unroll") for (int nf = 0; nf < 2; ++nf) { \
      f32x4 c_ = acc[(MH) * 4 + mf][(NH) * 2 + nf]; \
      c_ = __builtin_amdgcn_mfma_f32_16x16x32_bf16(aF[mf][0], BF[nf][0], c_, 0, 0, 0); \
      c_ = __builtin_amdgcn_mfma_f32_16x16x32_bf16(aF[mf][1], BF[nf][1], c_, 0, 0, 0); \
      acc[(MH) * 4 + mf][(NH) * 2 + nf] = c_; \
    } \
    __builtin_amdgcn_s_setprio(0); \
  } while (0)
#define WAITB(nstr) do { \
    asm volatile("s_waitcnt vmcnt(" nstr ")" ::: "memory"); BARX(); } while (0)

  f32x4 acc[8][4] = {};

  // prologue: 7 halves (14 loads): t0 all 4, t1 {Aq0, BL, BH}. Aq1[t1] is staged
  // in ph1. vmcnt(10) -> oldest 4 loads (Aq0[0], BL[0]) landed; barrier.
  STG_A(0, 0, 0); STG_B(0, 0, 0); STG_B(0, 1, 0); STG_A(0, 1, 0);
  STG_A(1, 0, 1); STG_B(1, 0, 1); STG_B(1, 1, 1);
  WAITB("10");

#pragma unroll
  for (int it = 0; it < 4; ++it) {        // 2 K-tiles per iteration, K = 512
    const int t0 = 2 * it, t1 = t0 + 1;
    const bool st = (it < 3);
    bf16x8 aF[4][2], bFa[2][2], bFb[2][2];

    // ph1: read Aq0[t0], B-L[t0]; stage Aq1[t1]->buf1; MFMA (m0,n0) of t0
    LOAD_A(0, 0); LOAD_B(0, 0, bFa);
    STG_A(1, 1, t1);
    MFMA_Q(0, 0, bFa);
    if (st) WAITB("10"); else WAITB("2");
    // ph2: read B-H[t0]; stage Aq0[t0+2]->buf0; MFMA (m0,n1)
    LOAD_B(0, 1, bFb);
    if (st) STG_A(0, 0, t0 + 2);
    MFMA_Q(0, 1, bFb);
    if (st) WAITB("10"); else WAITB("2");
    // ph3: read Aq1[t0]; stage B-L[t0+2]->buf0; MFMA (m1,n1)
    LOAD_A(0, 1);
    if (st) STG_B(0, 0, t0 + 2);
    MFMA_Q(1, 1, bFb);
    if (st) WAITB("10"); else WAITB("2");
    // ph4: regs only; stage B-H[t0+2]->buf0; MFMA (m1,n0)
    if (st) STG_B(0, 1, t0 + 2);
    MFMA_Q(1, 0, bFa);
    if (st) WAITB("10"); else WAITB("2");
    // ph5: read Aq0[t1], B-L[t1]; stage Aq1[t0+2]->buf0; MFMA (m0,n0) of t1
    LOAD_A(1, 0); LOAD_B(1, 0, bFa);
    if (st) STG_A(0, 1, t0 + 2);
    MFMA_Q(0, 0, bFa);
    if (st) WAITB("10"); else WAITB("2");
    // ph6: read B-H[t1]; stage Aq0[t1+2]->buf1; MFMA (m0,n1)
    LOAD_B(1, 1, bFb);
    if (st) STG_A(1, 0, t1 + 2);
    MFMA_Q(0, 1, bFb);
    if (st) WAITB("10"); else WAITB("0");
    // ph7: read Aq1[t1] (staged ph1); stage B-L[t1+2]->buf1; MFMA (m1,n1)
    LOAD_A(1, 1);
    if (st) STG_B(1, 0, t1 + 2);
    MFMA_Q(1, 1, bFb);
    if (st) WAITB("10"); else WAITB("0");
    // ph8: regs only; stage B-H[t1+2]->buf1; MFMA (m1,n0)
    if (st) STG_B(1, 1, t1 + 2);
    MFMA_Q(1, 0, bFa);
    if (st) WAITB("10"); else WAITB("0");
  }

  // ---- epilogue (r5-verified): per-wave LDS staging -> contiguous stores ----
  // acc[mi][n][j]: local row = mi*16 + g4*4 + j (0..127), local col = n*16 + ln15.
  __syncthreads();   // full drain; everyone done with sA/sB
  const long rgb = row0 + wr * 128;
  const int cgb = col0 + wc * 64;
  if (BF16OUT) {
    u16* sc = (u16*)(smem + (w << 14));      // 16 KiB/wave: [128][64] u16
#pragma unroll
    for (int n = 0; n < 4; ++n) {
      const int colg = cgb + ln15 + n * 16;
      const float* bp_ = (NC == 512) ? bias0
                         : (colg < 512 ? bias0 : (colg < 1024 ? bias1 : bias2));
      const float bv = bp_[colg & 511];
      const int c = ln15 + n * 16;
      const int gsl = c >> 3, co = c & 7;
#pragma unroll
      for (int mi = 0; mi < 8; ++mi)
#pragma unroll
        for (int j = 0; j < 4; ++j) {
          const int r = mi * 16 + (g4 << 2) + j;
          sc[r * 64 + (((gsl ^ (r & 7)) << 3) | co)] = f2b(acc[mi][n][j] + bv);
        }
    }
    asm volatile("s_waitcnt lgkmcnt(0)" ::: "memory");
    __builtin_amdgcn_sched_barrier(0);
#pragma unroll
    for (int it = 0; it < 16; ++it) {
      const int rr = it * 8 + (lane >> 3);
      const int gl = lane & 7;
      u16x8 v = *(const u16x8*)(sc + rr * 64 + ((gl ^ (rr & 7)) << 3));
      *(u16x8*)((u16*)Cout + (rgb + rr) * NC + cgb + gl * 8) = v;
    }
  } else {
    float* scf = (float*)(smem + (w << 14));  // 16 KiB/wave: [64][64] f32, 2 passes
#pragma unroll
    for (int h = 0; h < 2; ++h) {
#pragma unroll
      for (int n = 0; n < 4; ++n) {
        const int colg = cgb + ln15 + n * 16;
        const float bv = bias0[colg & 511];
        const int c = ln15 + n * 16;
        const int gsl = c >> 2, co = c & 3;
#pragma unroll
        for (int mf = 0; mf < 4; ++mf)
#pragma unroll
          for (int j = 0; j < 4; ++j) {
            const int r = mf * 16 + (g4 << 2) + j;
            scf[r * 64 + (((gsl ^ (r & 7)) << 2) | co)] = acc[h * 4 + mf][n][j] + bv;
          }
      }
      asm volatile("s_waitcnt lgkmcnt(0)" ::: "memory");
      __builtin_amdgcn_sched_barrier(0);
#pragma unroll
      for (int it = 0; it < 16; ++it) {
        const int rr = it * 4 + (lane >> 4);
        const int gl = lane & 15;
        f32x4 v = *(const f32x4*)(scf + rr * 64 + ((gl ^ (rr & 7)) << 2));
        *(f32x4*)((float*)Cout + (rgb + h * 64 + rr) * NC + cgb + gl * 4) = v;
      }
      asm volatile("s_waitcnt lgkmcnt(0)" ::: "memory");
      __builtin_amdgcn_sched_barrier(0);
    }
  }
#undef STG_A
#undef STG_B
#undef LOAD_A
#undef LOAD_B
#undef MFMA_Q
#undef WAITB
}

// ---------- attention: per-token 8x8 head-mix, one wave per token ----------
__global__ __launch_bounds__(256) void attn_k(const u16* __restrict__ PCS,
                                              u16* __restrict__ OUT)
{
  // per-wave f32 scratch: p[8][68], c[8][68], s[512], attn[64]  (pad 68 kills bank conflicts)
  __shared__ float L[4][1664];
  const int w = threadIdx.x >> 6, lane = threadIdx.x & 63;
  const long token = (long)blockIdx.x * 4 + w;
  float* Lw = L[w];
  const int C0 = 544, S0 = 1088, AT0 = 1600;
  const u16* rowp = PCS + token * 1536;
#pragma unroll
  for (int q = 0; q < 3; ++q) {
    u16x8 v = *(const u16x8*)(rowp + q * 512 + lane * 8);
    float* dst = (q < 2) ? (Lw + q * 544 + (lane >> 3) * 68 + (lane & 7) * 8)
                         : (Lw + S0 + lane * 8);
    f32x4 a = {b2f(v[0]), b2f(v[1]), b2f(v[2]), b2f(v[3])};
    f32x4 b = {b2f(v[4]), b2f(v[5]), b2f(v[6]), b2f(v[7])};
    *(f32x4*)dst = a;
    *(f32x4*)(dst + 4) = b;
  }
  // all data wave-local: no __syncthreads needed (wave-synchronous + in-order DS)
  const int h = lane >> 3, t = lane & 7;
  float sc = 0.f;
#pragma unroll
  for (int d = 0; d < 64; d += 4) {
    f32x4 pv = *(const f32x4*)(Lw + h * 68 + d);
    f32x4 cv = *(const f32x4*)(Lw + C0 + t * 68 + d);
    sc += pv[0]*cv[0] + pv[1]*cv[1] + pv[2]*cv[2] + pv[3]*cv[3];
  }
  sc *= 0.125f;  // 1/sqrt(D), D=64
  float mx = sc;
  mx = fmaxf(mx, __shfl_xor(mx, 1));
  mx = fmaxf(mx, __shfl_xor(mx, 2));
  mx = fmaxf(mx, __shfl_xor(mx, 4));
  float e = __expf(sc - mx);
  float sm = e;
  sm += __shfl_xor(sm, 1);
  sm += __shfl_xor(sm, 2);
  sm += __shfl_xor(sm, 4);
  Lw[AT0 + lane] = e / sm;
  float o[8] = {0, 0, 0, 0, 0, 0, 0, 0};
#pragma unroll
  for (int tt = 0; tt < 8; ++tt) {
    const float av = Lw[AT0 + h * 8 + tt];
    f32x4 s0 = *(const f32x4*)(Lw + S0 + tt * 64 + t * 8);
    f32x4 s1 = *(const f32x4*)(Lw + S0 + tt * 64 + t * 8 + 4);
    o[0] += av * s0[0]; o[1] += av * s0[1]; o[2] += av * s0[2]; o[3] += av * s0[3];
    o[4] += av * s1[0]; o[5] += av * s1[1]; o[6] += av * s1[2]; o[7] += av * s1[3];
  }
  u16x8 ov;
#pragma unroll
  for (int j = 0; j < 8; ++j) ov[j] = f2b(o[j]);
  // out element index within token = h*64 + (t*8+j) = lane*8+j -> coalesced 16B/lane
  *(u16x8*)(OUT + token * 512 + lane * 8) = ov;
}

extern "C" void kernel_launch(void* const* d_in, const int* in_sizes, int n_in,
                              void* d_out, int out_size, void* d_ws, size_t ws_size,
                              hipStream_t stream) {
  const float* x  = (const float*)d_in[0];
  const float* Wp = (const float*)d_in[1];
  const float* bp = (const float*)d_in[2];
  const float* Wc = (const float*)d_in[3];
  const float* bc = (const float*)d_in[4];
  const float* Ws = (const float*)d_in[5];
  const float* bs = (const float*)d_in[6];
  const float* Wo = (const float*)d_in[7];
  const float* bo = (const float*)d_in[8];

  char* ws = (char*)d_ws;
  u16* xb   = (u16*)ws;                      // 33,554,432 B  (x as bf16)
  u16* wall = (u16*)(ws + 33554432);         //  1,572,864 B  ([1536][512] Wp|Wc|Ws)
  u16* wob  = (u16*)(ws + 35127296);         //    524,288 B  ([512][512] Wo)
  u16* pcs  = (u16*)(ws + 35651584);         // 100,663,296 B ([32768][1536] p|c|s)
  u16* outb = xb;                            // overlay: xb dead after gemm1

  convert_k<<<2048, 256, 0, stream>>>(x, Wp, Wc, Ws, Wo, xb, wall, wob);
  gemm8<1536, true><<<768, 512, 0, stream>>>(xb, wall, bp, bc, bs, pcs);
  attn_k<<<8192, 256, 0, stream>>>(pcs, outb);
  gemm8<512, false><<<256, 512, 0, stream>>>(outb, wob, bo, bo, bo, d_out);
}